// Round 4
// baseline (234.662 us; speedup 1.0000x reference)
//
#include <hip/hip_runtime.h>

#define NQ 2048
#define NO 2048
#define NOC 32   // o-chunks of 64; P = [NOC][65][NQ] floats = 17.0 MB in d_ws

// ---------------------------------------------------------------------------
// Main: grid = 32 q-groups x 32 o-chunks = 1024 blocks, 256 thr, 4 blocks/CU.
// lane = q (all 4 waves share the 64-query group); wave w owns o-slice
// [oc*64 + w*16, +16). u[64] held in registers (computed in-block from
// pos_query + W1 combos); t-tile computed in-block into LDS (transposed).
// Phase A: logits (l-outer, LDS broadcast t). Phase B: h += e * h_obs row.
// Cross-wave combine: plain LDS stores, wave0 accumulates (no atomics).
// ---------------------------------------------------------------------------
__global__ __launch_bounds__(256, 4) void gano_main(
    const float* __restrict__ h_obs,
    const float* __restrict__ pos_obs,
    const float* __restrict__ pos_query,
    const float* __restrict__ W1,
    const float* __restrict__ b1,
    const float* __restrict__ W2,
    float* __restrict__ P)
{
    __shared__ __align__(16) float tl[64 * 68];  // t-tile [l][o] / h_obs tile [o][l] / combine buf [65][64]
    __shared__ float po[3 * 64];
    __shared__ __align__(16) float w1q[3 * 64];  // W1[0:3] + W1[6:9]
    __shared__ float w1o[3 * 64];                // W1[3:6] - W1[6:9]
    __shared__ __align__(16) float b1l[64];
    __shared__ __align__(16) float w2l[64];

    const int tid  = threadIdx.x;
    const int lane = tid & 63;
    const int wave = tid >> 6;
    const int qg    = blockIdx.x >> 5;   // 0..31
    const int oc    = blockIdx.x & 31;   // 0..31
    const int obase = oc * 64;
    const int q     = qg * 64 + lane;

    // ---- stage W1 combos / b1 / W2 (first 64 threads) ----
    if (tid < 64) {
        float w6 = W1[6 * 64 + tid], w7 = W1[7 * 64 + tid], w8 = W1[8 * 64 + tid];
        w1q[0 * 64 + tid] = W1[0 * 64 + tid] + w6;
        w1q[1 * 64 + tid] = W1[1 * 64 + tid] + w7;
        w1q[2 * 64 + tid] = W1[2 * 64 + tid] + w8;
        w1o[0 * 64 + tid] = W1[3 * 64 + tid] - w6;
        w1o[1 * 64 + tid] = W1[4 * 64 + tid] - w7;
        w1o[2 * 64 + tid] = W1[5 * 64 + tid] - w8;
        b1l[tid] = b1[tid];
        w2l[tid] = W2[tid];   // W2 shape (64,1)
    }
    // per-lane positions
    float pq0 = pos_query[q * 3 + 0];
    float pq1 = pos_query[q * 3 + 1];
    float pq2 = pos_query[q * 3 + 2];
    float po0 = pos_obs[(obase + lane) * 3 + 0];
    float po1 = pos_obs[(obase + lane) * 3 + 1];
    float po2 = pos_obs[(obase + lane) * 3 + 2];
    if (wave == 0) { po[0 * 64 + lane] = po0; po[1 * 64 + lane] = po1; po[2 * 64 + lane] = po2; }
    __syncthreads();

    // ---- u[64] in registers (b1 folded); lane = q ----
    float u[64];
#pragma unroll
    for (int l = 0; l < 64; ++l)
        u[l] = b1l[l] + pq0 * w1q[l] + pq1 * w1q[64 + l] + pq2 * w1q[128 + l];

    // ---- t-tile: lane = o_local, wave w computes l in [w*16, +16) ----
#pragma unroll
    for (int j = 0; j < 16; ++j) {
        int l = wave * 16 + j;
        tl[l * 68 + lane] = po0 * w1o[l] + po1 * w1o[64 + l] + po2 * w1o[128 + l];
    }
    __syncthreads();

    // ---- Phase A: logits for this wave's 16 o's ----
    float lg[16];
#pragma unroll
    for (int o = 0; o < 16; ++o) lg[o] = 0.f;
    const int ow = wave * 16;
#pragma unroll
    for (int lb = 0; lb < 16; ++lb) {
        float4 wv = *(const float4*)(w2l + lb * 4);
#pragma unroll
        for (int dl = 0; dl < 4; ++dl) {
            const int l = lb * 4 + dl;
            const float4* tr = (const float4*)(tl + l * 68 + ow);  // wave-uniform broadcast
            float ul = u[l];
            float wl = (dl == 0) ? wv.x : (dl == 1) ? wv.y : (dl == 2) ? wv.z : wv.w;
#pragma unroll
            for (int j = 0; j < 4; ++j) {
                float4 t4 = tr[j];
                lg[4 * j + 0] += wl * fmaxf(ul + t4.x, 0.f);
                lg[4 * j + 1] += wl * fmaxf(ul + t4.y, 0.f);
                lg[4 * j + 2] += wl * fmaxf(ul + t4.z, 0.f);
                lg[4 * j + 3] += wl * fmaxf(ul + t4.w, 0.f);
            }
        }
    }

    // ---- mask + exp (no max-tracking: logits O(1) by construction) ----
    float e[16], s = 0.f;
#pragma unroll
    for (int o = 0; o < 16; ++o) {
        float d0 = pq0 - po[0 * 64 + ow + o];
        float d1 = pq1 - po[1 * 64 + ow + o];
        float d2 = pq2 - po[2 * 64 + ow + o];
        float dd = d0 * d0 + d1 * d1 + d2 * d2;
        float ev = (dd > 0.25f) ? 0.f : __expf(lg[o]);
        e[o] = ev; s += ev;
    }
    __syncthreads();   // all waves done reading t-tile

    // ---- stage h_obs tile [o][l] into tl (coalesced float4) ----
    {
        const float4* src = (const float4*)(h_obs + (size_t)obase * 64);
        float4* dst = (float4*)tl;
#pragma unroll
        for (int k = 0; k < 4; ++k) dst[tid + k * 256] = src[tid + k * 256];
    }
    __syncthreads();

    // ---- Phase B: h[l] += e_o * h_obs[obase+ow+o][l] ----
    float h[64];
#pragma unroll
    for (int l = 0; l < 64; ++l) h[l] = 0.f;
#pragma unroll
    for (int o = 0; o < 16; ++o) {
        float ev = e[o];
        const float4* hr = (const float4*)(tl + (ow + o) * 64);  // broadcast
#pragma unroll
        for (int j = 0; j < 16; ++j) {
            float4 h4 = hr[j];
            h[4 * j + 0] += ev * h4.x;
            h[4 * j + 1] += ev * h4.y;
            h[4 * j + 2] += ev * h4.z;
            h[4 * j + 3] += ev * h4.w;
        }
    }
    __syncthreads();   // done reading h_obs tile; tl free for combine

    // ---- cross-wave combine: plain LDS stores, wave0 accumulates ----
    for (int r = 1; r <= 3; ++r) {
        if (wave == r) {
#pragma unroll
            for (int l = 0; l < 64; ++l) tl[l * 64 + lane] = h[l];
            tl[64 * 64 + lane] = s;
        }
        __syncthreads();
        if (wave == 0) {
#pragma unroll
            for (int l = 0; l < 64; ++l) h[l] += tl[l * 64 + lane];
            s += tl[64 * 64 + lane];
        }
        __syncthreads();
    }

    // ---- block partial -> P[oc][l][q], coalesced plain stores ----
    if (wave == 0) {
        float* Pq = P + (size_t)oc * 65 * 2048 + (size_t)qg * 64 + lane;
#pragma unroll
        for (int l = 0; l < 64; ++l) Pq[(size_t)l * 2048] = h[l];
        Pq[(size_t)64 * 2048] = s;
    }
}

// ---------------------------------------------------------------------------
// Combine+finalize: grid = 32 blocks (one per q-group of 64).
// g[q][k] = sum_oc P[oc][k][q]; out[q][l] = (g[q][:]/s[q]) @ Wv + bv.
// Wv column held in registers (lane = l); g rows broadcast from LDS.
// ---------------------------------------------------------------------------
__global__ __launch_bounds__(256, 4) void gano_comb(
    const float* __restrict__ P,
    const float* __restrict__ Wv,
    const float* __restrict__ bv,
    float* __restrict__ out)
{
    __shared__ __align__(16) float g[64 * 68];   // [qloc][k], padded to 68
    const int tid  = threadIdx.x;
    const int lane = tid & 63;
    const int wave = tid >> 6;
    const int qg = blockIdx.x;

    // Wv column in registers: wv_r[k] = Wv[k][lane]
    float wv_r[64];
#pragma unroll 8
    for (int k = 0; k < 64; ++k) wv_r[k] = Wv[k * 64 + lane];
    float bvl = bv[lane];

    // g[qloc][k] = sum over 32 chunks (coalesced: consecutive tid = consecutive q)
#pragma unroll
    for (int it = 0; it < 17; ++it) {
        int idx = it * 256 + tid;
        int k = idx >> 6, qloc = idx & 63;
        if (k < 65) {
            const float* p = P + (size_t)k * 2048 + (size_t)qg * 64 + qloc;
            float acc = 0.f;
#pragma unroll
            for (int c = 0; c < NOC; ++c) acc += p[(size_t)c * 65 * 2048];
            g[qloc * 68 + k] = acc;
        }
    }
    __syncthreads();

    // wave w handles q = w*16 + j; lane = output latent l
    const int l = lane;
#pragma unroll
    for (int j = 0; j < 16; ++j) {
        const int qloc = wave * 16 + j;
        const float4* gq = (const float4*)(g + qloc * 68);   // wave-uniform broadcast
        float inv = 1.0f / g[qloc * 68 + 64];
        float a0 = 0.f, a1 = 0.f, a2 = 0.f, a3 = 0.f;
#pragma unroll
        for (int kb = 0; kb < 16; ++kb) {
            float4 g4 = gq[kb];
            a0 += g4.x * wv_r[kb * 4 + 0];
            a1 += g4.y * wv_r[kb * 4 + 1];
            a2 += g4.z * wv_r[kb * 4 + 2];
            a3 += g4.w * wv_r[kb * 4 + 3];
        }
        out[((size_t)qg * 64 + qloc) * 64 + l] = ((a0 + a1) + (a2 + a3)) * inv + bvl;
    }
}

// ---------------------------------------------------------------------------
extern "C" void kernel_launch(void* const* d_in, const int* in_sizes, int n_in,
                              void* d_out, int out_size, void* d_ws, size_t ws_size,
                              hipStream_t stream) {
    const float* h_obs     = (const float*)d_in[0];
    // d_in[1] = x_obs (unused by reference)
    const float* pos_obs   = (const float*)d_in[2];
    const float* pos_query = (const float*)d_in[3];
    const float* W1        = (const float*)d_in[4];
    const float* b1        = (const float*)d_in[5];
    const float* W2        = (const float*)d_in[6];
    // d_in[7] = b2: constant shift, cancels in softmax
    const float* Wv        = (const float*)d_in[8];
    const float* bv        = (const float*)d_in[9];
    float* P   = (float*)d_ws;           // [NOC][65][2048] = 17.0 MB
    float* out = (float*)d_out;

    gano_main<<<dim3(1024), dim3(256), 0, stream>>>(h_obs, pos_obs, pos_query, W1, b1, W2, P);
    gano_comb<<<dim3(32), dim3(256), 0, stream>>>(P, Wv, bv, out);
}

// Round 5
// 121.891 us; speedup vs baseline: 1.9252x; 1.9252x over previous
//
#include <hip/hip_runtime.h>

#define NQ 2048
#define NO 2048
#define NOC 16   // o-chunks of 128 (2 tiles of 64 each)

// workspace layout (float offsets)
// P: [NOC][2048 q][68] (j<64: h partial, j=64: s partial, 65..67 pad) = 8.9 MB
constexpr size_t OFF_P = 0;
constexpr size_t P_ROW = 68;
constexpr size_t OFF_V = (size_t)NOC * NQ * P_ROW;   // V[o][l] = h_obs @ Wv : 2048*64
// total = 2,359,296 floats = 9.44 MB (fits proven >=10.3 MB ws)

// ---------------------------------------------------------------------------
// Prep: V = h_obs @ Wv (no bv; bv added after normalization in comb).
// 512 blocks x 4 waves = 1 row per wave; lane = output latent l.
// Wv staged in LDS [k][l] (lane-consecutive reads, conflict-free).
// ---------------------------------------------------------------------------
__global__ __launch_bounds__(256, 2) void gano_prep(
    const float* __restrict__ h_obs,
    const float* __restrict__ Wv,
    float* __restrict__ ws)
{
    __shared__ __align__(16) float wv[64 * 64];
    const int tid  = threadIdx.x;
    const int lane = tid & 63;
    const int wave = tid >> 6;
    {
        const float4* src = (const float4*)Wv;
        float4* dst = (float4*)wv;
#pragma unroll
        for (int k = 0; k < 4; ++k) dst[tid + k * 256] = src[tid + k * 256];
    }
    __syncthreads();
    const int o = blockIdx.x * 4 + wave;
    const float4* hp = (const float4*)(h_obs + (size_t)o * 64);  // wave-uniform
    float a0 = 0.f, a1 = 0.f, a2 = 0.f, a3 = 0.f;
#pragma unroll
    for (int kb = 0; kb < 16; ++kb) {
        float4 h4 = hp[kb];
        a0 += h4.x * wv[(kb * 4 + 0) * 64 + lane];
        a1 += h4.y * wv[(kb * 4 + 1) * 64 + lane];
        a2 += h4.z * wv[(kb * 4 + 2) * 64 + lane];
        a3 += h4.w * wv[(kb * 4 + 3) * 64 + lane];
    }
    ws[OFF_V + (size_t)o * 64 + lane] = (a0 + a1) + (a2 + a3);
}

// ---------------------------------------------------------------------------
// Main: 512 blocks = 32 q-groups x 16 o-chunks(128). lane = q; wave w owns
// o-slice [tile + w*16, +16). u[64], h[64] in REGISTERS (launch_bounds(256,2)
// gives a 256-VGPR budget; (256,4) in R3/R4 capped at <=128 and spilled both
// arrays to scratch -> 55 MB WRITE_SIZE, latency disaster).
// Per o-tile of 64: compute t-tile in LDS, phase A logits (LDS broadcasts),
// exp+mask, stage V tile, phase B accumulate. Combine via plain LDS (stride
// 65 = conflict-free), store P[oc][q][68] coalesced via LDS transpose.
// ---------------------------------------------------------------------------
__global__ __launch_bounds__(256, 2) void gano_main(
    const float* __restrict__ ws,
    const float* __restrict__ pos_obs,
    const float* __restrict__ pos_query,
    const float* __restrict__ W1,
    const float* __restrict__ b1,
    const float* __restrict__ W2,
    float* __restrict__ P)
{
    __shared__ __align__(16) float tl[64 * 68];  // t-tile [l][o]s68 / V-tile [o][l]s64 / combine [j][q]s65
    __shared__ float po[3 * 64];
    __shared__ float w1q[3 * 64];                // W1[0:3] + W1[6:9]
    __shared__ float w1o[3 * 64];                // W1[3:6] - W1[6:9]
    __shared__ float b1l[64];
    __shared__ __align__(16) float w2l[64];

    const int tid  = threadIdx.x;
    const int lane = tid & 63;
    const int wave = tid >> 6;
    const int qg = blockIdx.x >> 4;   // 0..31
    const int oc = blockIdx.x & 15;   // 0..15
    const int q  = qg * 64 + lane;

    if (tid < 64) {
        float w6 = W1[6 * 64 + tid], w7 = W1[7 * 64 + tid], w8 = W1[8 * 64 + tid];
        w1q[0 * 64 + tid] = W1[0 * 64 + tid] + w6;
        w1q[1 * 64 + tid] = W1[1 * 64 + tid] + w7;
        w1q[2 * 64 + tid] = W1[2 * 64 + tid] + w8;
        w1o[0 * 64 + tid] = W1[3 * 64 + tid] - w6;
        w1o[1 * 64 + tid] = W1[4 * 64 + tid] - w7;
        w1o[2 * 64 + tid] = W1[5 * 64 + tid] - w8;
        b1l[tid] = b1[tid];
        w2l[tid] = W2[tid];   // W2 shape (64,1)
    }
    float pq0 = pos_query[q * 3 + 0];
    float pq1 = pos_query[q * 3 + 1];
    float pq2 = pos_query[q * 3 + 2];
    __syncthreads();

    float u[64];
#pragma unroll
    for (int l = 0; l < 64; ++l)
        u[l] = b1l[l] + pq0 * w1q[l] + pq1 * w1q[64 + l] + pq2 * w1q[128 + l];

    float h[64];
#pragma unroll
    for (int l = 0; l < 64; ++l) h[l] = 0.f;
    float s = 0.f;
    const int ow = wave * 16;

    for (int ot = 0; ot < 2; ++ot) {
        const int obase = oc * 128 + ot * 64;
        // lane = o_local for t-tile / po
        float po0 = pos_obs[(obase + lane) * 3 + 0];
        float po1 = pos_obs[(obase + lane) * 3 + 1];
        float po2 = pos_obs[(obase + lane) * 3 + 2];
        if (wave == 0) { po[lane] = po0; po[64 + lane] = po1; po[128 + lane] = po2; }
#pragma unroll
        for (int j = 0; j < 16; ++j) {
            int l = wave * 16 + j;
            tl[l * 68 + lane] = po0 * w1o[l] + po1 * w1o[64 + l] + po2 * w1o[128 + l];
        }
        __syncthreads();

        // ---- Phase A: logits for this wave's 16 o's ----
        float lg[16];
#pragma unroll
        for (int o = 0; o < 16; ++o) lg[o] = 0.f;
#pragma unroll
        for (int lb = 0; lb < 16; ++lb) {
            float4 wv = *(const float4*)(w2l + lb * 4);
#pragma unroll
            for (int dl = 0; dl < 4; ++dl) {
                const int l = lb * 4 + dl;
                const float4* tr = (const float4*)(tl + l * 68 + ow);  // broadcast
                float ul = u[l];
                float wl = (dl == 0) ? wv.x : (dl == 1) ? wv.y : (dl == 2) ? wv.z : wv.w;
#pragma unroll
                for (int j = 0; j < 4; ++j) {
                    float4 t4 = tr[j];
                    lg[4 * j + 0] += wl * fmaxf(ul + t4.x, 0.f);
                    lg[4 * j + 1] += wl * fmaxf(ul + t4.y, 0.f);
                    lg[4 * j + 2] += wl * fmaxf(ul + t4.z, 0.f);
                    lg[4 * j + 3] += wl * fmaxf(ul + t4.w, 0.f);
                }
            }
        }
        // ---- mask + exp (logits O(1): raw exp safe, no max tracking) ----
        float e[16];
#pragma unroll
        for (int o = 0; o < 16; ++o) {
            float d0 = pq0 - po[ow + o];
            float d1 = pq1 - po[64 + ow + o];
            float d2 = pq2 - po[128 + ow + o];
            float dd = d0 * d0 + d1 * d1 + d2 * d2;
            float ev = (dd > 0.25f) ? 0.f : __expf(lg[o]);
            e[o] = ev; s += ev;
        }
        __syncthreads();   // all waves done with t-tile + po

        // ---- stage V tile [o][l] (coalesced float4) ----
        {
            const float4* src = (const float4*)(ws + OFF_V + (size_t)obase * 64);
            float4* dst = (float4*)tl;
#pragma unroll
            for (int k = 0; k < 4; ++k) dst[tid + k * 256] = src[tid + k * 256];
        }
        __syncthreads();

        // ---- Phase B: h[l] += e_o * V[obase+ow+o][l] ----
#pragma unroll
        for (int o = 0; o < 16; ++o) {
            float ev = e[o];
            const float4* vr = (const float4*)(tl + (ow + o) * 64);  // broadcast
#pragma unroll
            for (int j = 0; j < 16; ++j) {
                float4 v4 = vr[j];
                h[4 * j + 0] += ev * v4.x;
                h[4 * j + 1] += ev * v4.y;
                h[4 * j + 2] += ev * v4.z;
                h[4 * j + 3] += ev * v4.w;
            }
        }
        __syncthreads();   // V tile free before next iteration's t-tile
    }

    // ---- cross-wave combine: stride 65 (conflict-free), no atomics ----
    for (int r = 1; r <= 3; ++r) {
        if (wave == r) {
#pragma unroll
            for (int l = 0; l < 64; ++l) tl[l * 65 + lane] = h[l];
            tl[64 * 65 + lane] = s;
        }
        __syncthreads();
        if (wave == 0) {
#pragma unroll
            for (int l = 0; l < 64; ++l) h[l] += tl[l * 65 + lane];
            s += tl[64 * 65 + lane];
        }
        __syncthreads();
    }
    if (wave == 0) {
#pragma unroll
        for (int l = 0; l < 64; ++l) tl[l * 65 + lane] = h[l];
        tl[64 * 65 + lane] = s;
    }
    __syncthreads();

    // ---- coalesced transposed store: P[oc][q][j], row stride 68 ----
    {
        float* base = P + ((size_t)oc * NQ + (size_t)qg * 64) * P_ROW;
#pragma unroll
        for (int k = 0; k < 17; ++k) {
            int idx = k * 256 + tid;          // covers 64*68 = 4352
            int qloc = idx / 68, j = idx % 68;
            float v = 0.f;
            if (j < 65) v = tl[j * 65 + qloc];
            base[idx] = v;
        }
    }
}

// ---------------------------------------------------------------------------
// Combine: out[q][l] = (sum_c P[c][q][l]) / (sum_c P[c][q][64]) + bv[l].
// 512 blocks x 256 thr; block = 4 q x 64 l; everything coalesced.
// ---------------------------------------------------------------------------
__global__ __launch_bounds__(256) void gano_comb(
    const float* __restrict__ P,
    const float* __restrict__ bv,
    float* __restrict__ out)
{
    const int tid = threadIdx.x;
    const int l = tid & 63;
    const int qi = tid >> 6;
    const int q = blockIdx.x * 4 + qi;
    float hs = 0.f, ss = 0.f;
#pragma unroll
    for (int c = 0; c < NOC; ++c) {
        const float* row = P + ((size_t)c * NQ + q) * P_ROW;
        hs += row[l];       // coalesced
        ss += row[64];      // wave-uniform broadcast
    }
    out[(size_t)q * 64 + l] = hs / ss + bv[l];
}

// ---------------------------------------------------------------------------
extern "C" void kernel_launch(void* const* d_in, const int* in_sizes, int n_in,
                              void* d_out, int out_size, void* d_ws, size_t ws_size,
                              hipStream_t stream) {
    const float* h_obs     = (const float*)d_in[0];
    // d_in[1] = x_obs (unused by reference)
    const float* pos_obs   = (const float*)d_in[2];
    const float* pos_query = (const float*)d_in[3];
    const float* W1        = (const float*)d_in[4];
    const float* b1        = (const float*)d_in[5];
    const float* W2        = (const float*)d_in[6];
    // d_in[7] = b2: constant shift, cancels in softmax
    const float* Wv        = (const float*)d_in[8];
    const float* bv        = (const float*)d_in[9];
    float* ws  = (float*)d_ws;
    float* out = (float*)d_out;

    gano_prep<<<dim3(NO / 4), dim3(256), 0, stream>>>(h_obs, Wv, ws);
    gano_main<<<dim3(512), dim3(256), 0, stream>>>(ws, pos_obs, pos_query, W1, b1, W2, ws + OFF_P);
    gano_comb<<<dim3(NQ / 4), dim3(256), 0, stream>>>(ws + OFF_P, bv, out);
}

// Round 6
// 108.998 us; speedup vs baseline: 2.1529x; 1.1183x over previous
//
#include <hip/hip_runtime.h>

#define NQ 2048
#define NO 2048
#define NOC 32   // o-chunks of 64

// ws layout (float offsets): P_h [NOC][2048][64], P_s [NOC][2048]
// total = 17,039,360 B — exactly the footprint proven to fit in R4.
constexpr size_t OFF_PH = 0;
constexpr size_t OFF_PS = (size_t)NOC * NQ * 64;
// V[2048][64] (= h_obs @ Wv, no bv) lives in d_out between prep and comb.

// ---------------------------------------------------------------------------
// Prep: V = h_obs @ Wv -> d_out (scratch; comb overwrites it at the end).
// One row per wave; lane = output latent l; Wv staged in LDS.
// ---------------------------------------------------------------------------
__global__ __launch_bounds__(256, 2) void gano_prep(
    const float* __restrict__ h_obs,
    const float* __restrict__ Wv,
    float* __restrict__ V)
{
    __shared__ __align__(16) float wv[64 * 64];
    const int tid  = threadIdx.x;
    const int lane = tid & 63;
    const int wave = tid >> 6;
    {
        const float4* src = (const float4*)Wv;
        float4* dst = (float4*)wv;
#pragma unroll
        for (int k = 0; k < 4; ++k) dst[tid + k * 256] = src[tid + k * 256];
    }
    __syncthreads();
    const int o = blockIdx.x * 4 + wave;
    const float4* hp = (const float4*)(h_obs + (size_t)o * 64);  // wave-uniform
    float a0 = 0.f, a1 = 0.f, a2 = 0.f, a3 = 0.f;
#pragma unroll
    for (int kb = 0; kb < 16; ++kb) {
        float4 h4 = hp[kb];
        a0 += h4.x * wv[(kb * 4 + 0) * 64 + lane];
        a1 += h4.y * wv[(kb * 4 + 1) * 64 + lane];
        a2 += h4.z * wv[(kb * 4 + 2) * 64 + lane];
        a3 += h4.w * wv[(kb * 4 + 3) * 64 + lane];
    }
    V[(size_t)o * 64 + lane] = (a0 + a1) + (a2 + a3);
}

// ---------------------------------------------------------------------------
// Main: 1024 blocks = 32 q-groups x 32 o-chunks(64); 4 blocks/CU (37.6 KB LDS).
// No u[64]/h[64] register arrays (R5's AGPR-shuffle + 2-waves/SIMD trap):
//   u  -> LDS [lb][q] float4 tile (1 ds_read_b128 per lb in phase A)
//   h  -> phase B role-switch: wave w computes l-slice [16w,16w+16) over ALL
//         64 o's (e from LDS [o][q]); disjoint outputs => no cross-wave
//         combine at all.
// ---------------------------------------------------------------------------
__global__ __launch_bounds__(256, 4) void gano_main(
    const float* __restrict__ V,
    const float* __restrict__ pos_obs,
    const float* __restrict__ pos_query,
    const float* __restrict__ W1,
    const float* __restrict__ b1,
    const float* __restrict__ W2,
    float* __restrict__ Ph,
    float* __restrict__ Ps)
{
    __shared__ __align__(16) float tl[64 * 68];    // t [l][o] stride 68 (16B-aligned rows)
    __shared__ __align__(16) float ue[16 * 64 * 4]; // phase A: u4 [lb][q]; after sync2: e [o][q]
    __shared__ float w1q[3 * 64];                  // W1[0:3] + W1[6:9]
    __shared__ float w1o[3 * 64];                  // W1[3:6] - W1[6:9]
    __shared__ float b1l[64];
    __shared__ __align__(16) float w2l[64];
    __shared__ float po[3 * 64];
    __shared__ float sbuf[4 * 64];

    const int tid  = threadIdx.x;
    const int lane = tid & 63;
    const int wave = __builtin_amdgcn_readfirstlane(tid >> 6);
    const int qg = blockIdx.x >> 5;   // 0..31
    const int oc = blockIdx.x & 31;   // 0..31
    const int obase = oc * 64;
    const int q = qg * 64 + lane;

    if (tid < 64) {
        float w6 = W1[6 * 64 + tid], w7 = W1[7 * 64 + tid], w8 = W1[8 * 64 + tid];
        w1q[0 * 64 + tid] = W1[0 * 64 + tid] + w6;
        w1q[1 * 64 + tid] = W1[1 * 64 + tid] + w7;
        w1q[2 * 64 + tid] = W1[2 * 64 + tid] + w8;
        w1o[0 * 64 + tid] = W1[3 * 64 + tid] - w6;
        w1o[1 * 64 + tid] = W1[4 * 64 + tid] - w7;
        w1o[2 * 64 + tid] = W1[5 * 64 + tid] - w8;
        b1l[tid] = b1[tid];
        w2l[tid] = W2[tid];   // W2 shape (64,1)
    }
    float pq0 = pos_query[q * 3 + 0];
    float pq1 = pos_query[q * 3 + 1];
    float pq2 = pos_query[q * 3 + 2];
    float po0 = pos_obs[(obase + lane) * 3 + 0];   // lane = o_local here
    float po1 = pos_obs[(obase + lane) * 3 + 1];
    float po2 = pos_obs[(obase + lane) * 3 + 2];
    if (wave == 0) { po[lane] = po0; po[64 + lane] = po1; po[128 + lane] = po2; }
    __syncthreads();   // sync0: weight staging visible

    // ---- t-tile: lane = o_local, wave w computes l in [16w,16w+16) ----
#pragma unroll
    for (int j = 0; j < 16; ++j) {
        int l = wave * 16 + j;
        tl[l * 68 + lane] = po0 * w1o[l] + po1 * w1o[64 + l] + po2 * w1o[128 + l];
    }
    // ---- u-tile [lb][q] float4: wave w computes lb in [4w,4w+4) ----
#pragma unroll
    for (int k = 0; k < 4; ++k) {
        int lb = wave * 4 + k;
        float4 uv;
        {
            int l = lb * 4;
            uv.x = b1l[l+0] + pq0 * w1q[l+0] + pq1 * w1q[64 + l+0] + pq2 * w1q[128 + l+0];
            uv.y = b1l[l+1] + pq0 * w1q[l+1] + pq1 * w1q[64 + l+1] + pq2 * w1q[128 + l+1];
            uv.z = b1l[l+2] + pq0 * w1q[l+2] + pq1 * w1q[64 + l+2] + pq2 * w1q[128 + l+2];
            uv.w = b1l[l+3] + pq0 * w1q[l+3] + pq1 * w1q[64 + l+3] + pq2 * w1q[128 + l+3];
        }
        *(float4*)(ue + (size_t)(lb * 64 + lane) * 4) = uv;
    }
    __syncthreads();   // sync1: tiles ready

    // ---- Phase A: wave w -> o-slice [16w,16w+16), lane = q ----
    float lg[16];
#pragma unroll
    for (int o = 0; o < 16; ++o) lg[o] = 0.f;
    const int ow = wave * 16;
#pragma unroll
    for (int lb = 0; lb < 16; ++lb) {
        float4 u4 = *(const float4*)(ue + (size_t)(lb * 64 + lane) * 4);  // conflict-free b128
        float4 w4 = *(const float4*)(w2l + lb * 4);                        // broadcast
#pragma unroll
        for (int dl = 0; dl < 4; ++dl) {
            const int l = lb * 4 + dl;
            const float4* tr = (const float4*)(tl + l * 68 + ow);          // broadcast
            float ul = (dl == 0) ? u4.x : (dl == 1) ? u4.y : (dl == 2) ? u4.z : u4.w;
            float wl = (dl == 0) ? w4.x : (dl == 1) ? w4.y : (dl == 2) ? w4.z : w4.w;
#pragma unroll
            for (int j = 0; j < 4; ++j) {
                float4 t4 = tr[j];
                lg[4 * j + 0] += wl * fmaxf(ul + t4.x, 0.f);
                lg[4 * j + 1] += wl * fmaxf(ul + t4.y, 0.f);
                lg[4 * j + 2] += wl * fmaxf(ul + t4.z, 0.f);
                lg[4 * j + 3] += wl * fmaxf(ul + t4.w, 0.f);
            }
        }
    }
    // ---- mask + exp (logits O(1): raw exp safe) ----
    float e[16], spart = 0.f;
#pragma unroll
    for (int o = 0; o < 16; ++o) {
        float d0 = pq0 - po[ow + o];
        float d1 = pq1 - po[64 + ow + o];
        float d2 = pq2 - po[128 + ow + o];
        float dd = d0 * d0 + d1 * d1 + d2 * d2;
        float ev = (dd > 0.25f) ? 0.f : __expf(lg[o]);
        e[o] = ev; spart += ev;
    }
    __syncthreads();   // sync2: phase A done reading ue -> reuse as e-buf
#pragma unroll
    for (int o = 0; o < 16; ++o) ue[(size_t)(ow + o) * 64 + lane] = e[o];  // conflict-free
    sbuf[wave * 64 + lane] = spart;
    __syncthreads();   // sync3: e-buf ready

    // ---- Phase B: wave w -> l-slice [16w,16w+16), full 64 o's ----
    float h0 = 0.f, h1 = 0.f, h2 = 0.f, h3 = 0.f, h4 = 0.f, h5 = 0.f, h6 = 0.f, h7 = 0.f;
    float h8 = 0.f, h9 = 0.f, hA = 0.f, hB = 0.f, hC = 0.f, hD = 0.f, hE = 0.f, hF = 0.f;
    const float* vb = V + (size_t)obase * 64 + ow;   // ow doubles as l-offset
#pragma unroll 4
    for (int o = 0; o < 64; ++o) {
        float eo = ue[(size_t)o * 64 + lane];        // b32, lane-consecutive
        const float4* vr = (const float4*)(vb + (size_t)o * 64);  // wave-uniform
        float4 v0 = vr[0], v1 = vr[1], v2 = vr[2], v3 = vr[3];
        h0 += eo * v0.x; h1 += eo * v0.y; h2 += eo * v0.z; h3 += eo * v0.w;
        h4 += eo * v1.x; h5 += eo * v1.y; h6 += eo * v1.z; h7 += eo * v1.w;
        h8 += eo * v2.x; h9 += eo * v2.y; hA += eo * v2.z; hB += eo * v2.w;
        hC += eo * v3.x; hD += eo * v3.y; hE += eo * v3.z; hF += eo * v3.w;
    }

    // ---- store partials (disjoint per wave, no combine) ----
    float* hp = Ph + ((size_t)oc * NQ + (size_t)qg * 64 + lane) * 64 + ow;
    ((float4*)hp)[0] = make_float4(h0, h1, h2, h3);
    ((float4*)hp)[1] = make_float4(h4, h5, h6, h7);
    ((float4*)hp)[2] = make_float4(h8, h9, hA, hB);
    ((float4*)hp)[3] = make_float4(hC, hD, hE, hF);
    if (wave == 0) {
        float s = sbuf[lane] + sbuf[64 + lane] + sbuf[128 + lane] + sbuf[192 + lane];
        Ps[(size_t)oc * NQ + (size_t)qg * 64 + lane] = s;
    }
}

// ---------------------------------------------------------------------------
// Combine: out[q][l] = (sum_c Ph[c][q][l]) / (sum_c Ps[c][q]) + bv[l].
// 512 blocks x 256 thr; block = 4 q x 64 l; fully coalesced.
// ---------------------------------------------------------------------------
__global__ __launch_bounds__(256) void gano_comb(
    const float* __restrict__ Ph,
    const float* __restrict__ Ps,
    const float* __restrict__ bv,
    float* __restrict__ out)
{
    const int tid = threadIdx.x;
    const int l = tid & 63;
    const int qi = tid >> 6;
    const int q = blockIdx.x * 4 + qi;
    float hs = 0.f, ss = 0.f;
#pragma unroll
    for (int c = 0; c < NOC; ++c) {
        hs += Ph[((size_t)c * NQ + q) * 64 + l];   // coalesced
        ss += Ps[(size_t)c * NQ + q];              // uniform within wave-quarter
    }
    out[(size_t)q * 64 + l] = hs / ss + bv[l];
}

// ---------------------------------------------------------------------------
extern "C" void kernel_launch(void* const* d_in, const int* in_sizes, int n_in,
                              void* d_out, int out_size, void* d_ws, size_t ws_size,
                              hipStream_t stream) {
    const float* h_obs     = (const float*)d_in[0];
    // d_in[1] = x_obs (unused by reference)
    const float* pos_obs   = (const float*)d_in[2];
    const float* pos_query = (const float*)d_in[3];
    const float* W1        = (const float*)d_in[4];
    const float* b1        = (const float*)d_in[5];
    const float* W2        = (const float*)d_in[6];
    // d_in[7] = b2: constant shift, cancels in softmax
    const float* Wv        = (const float*)d_in[8];
    const float* bv        = (const float*)d_in[9];
    float* ws  = (float*)d_ws;
    float* out = (float*)d_out;   // also used as V scratch between prep and comb

    gano_prep<<<dim3(NO / 4), dim3(256), 0, stream>>>(h_obs, Wv, out);
    gano_main<<<dim3(1024), dim3(256), 0, stream>>>(out, pos_obs, pos_query, W1, b1, W2,
                                                    ws + OFF_PH, ws + OFF_PS);
    gano_comb<<<dim3(NQ / 4), dim3(256), 0, stream>>>(ws + OFF_PH, ws + OFF_PS, bv, out);
}

// Round 7
// 108.245 us; speedup vs baseline: 2.1679x; 1.0070x over previous
//
#include <hip/hip_runtime.h>

#define NQ 2048
#define NO 2048
#define NOC 32   // o-chunks of 64

// ws layout (float offsets): P_h [NOC][2048][64] (= sum_o e*h_obs, pre-Wv),
// P_s [NOC][2048]. 17.04 MB total; ws_size ~256 MiB (fill counter evidence R6).
constexpr size_t OFF_PH = 0;
constexpr size_t OFF_PS = (size_t)NOC * NQ * 64;

// ---------------------------------------------------------------------------
// Main: 1024 blocks = 32 q-groups x 32 o-chunks(64); 4 blocks/CU (37.6 KB LDS).
// lane=q. u -> LDS [lb][q] float4 tile; phase A: wave w computes logits for
// o-slice [16w,+16); phase B role-switch: wave w computes l-slice [16w,+16)
// over all 64 o's, accumulating RAW h_obs rows (Wv applied post-normalize in
// comb — linearity). Disjoint outputs => no cross-wave combine, no atomics.
// ---------------------------------------------------------------------------
__global__ __launch_bounds__(256, 4) void gano_main(
    const float* __restrict__ h_obs,
    const float* __restrict__ pos_obs,
    const float* __restrict__ pos_query,
    const float* __restrict__ W1,
    const float* __restrict__ b1,
    const float* __restrict__ W2,
    float* __restrict__ Ph,
    float* __restrict__ Ps)
{
    __shared__ __align__(16) float tl[64 * 68];     // t [l][o] stride 68
    __shared__ __align__(16) float ue[16 * 64 * 4]; // phase A: u4 [lb][q]; after sync2: e [o][q]
    __shared__ float w1q[3 * 64];                   // W1[0:3] + W1[6:9]
    __shared__ float w1o[3 * 64];                   // W1[3:6] - W1[6:9]
    __shared__ float b1l[64];
    __shared__ __align__(16) float w2l[64];
    __shared__ float po[3 * 64];
    __shared__ float sbuf[4 * 64];

    const int tid  = threadIdx.x;
    const int lane = tid & 63;
    const int wave = __builtin_amdgcn_readfirstlane(tid >> 6);
    const int qg = blockIdx.x >> 5;   // 0..31
    const int oc = blockIdx.x & 31;   // 0..31
    const int obase = oc * 64;
    const int q = qg * 64 + lane;

    if (tid < 64) {
        float w6 = W1[6 * 64 + tid], w7 = W1[7 * 64 + tid], w8 = W1[8 * 64 + tid];
        w1q[0 * 64 + tid] = W1[0 * 64 + tid] + w6;
        w1q[1 * 64 + tid] = W1[1 * 64 + tid] + w7;
        w1q[2 * 64 + tid] = W1[2 * 64 + tid] + w8;
        w1o[0 * 64 + tid] = W1[3 * 64 + tid] - w6;
        w1o[1 * 64 + tid] = W1[4 * 64 + tid] - w7;
        w1o[2 * 64 + tid] = W1[5 * 64 + tid] - w8;
        b1l[tid] = b1[tid];
        w2l[tid] = W2[tid];   // W2 shape (64,1)
    }
    float pq0 = pos_query[q * 3 + 0];
    float pq1 = pos_query[q * 3 + 1];
    float pq2 = pos_query[q * 3 + 2];
    float po0 = pos_obs[(obase + lane) * 3 + 0];   // lane = o_local here
    float po1 = pos_obs[(obase + lane) * 3 + 1];
    float po2 = pos_obs[(obase + lane) * 3 + 2];
    if (wave == 0) { po[lane] = po0; po[64 + lane] = po1; po[128 + lane] = po2; }
    __syncthreads();   // sync0: weight staging visible

    // ---- t-tile: lane = o_local, wave w computes l in [16w,16w+16) ----
#pragma unroll
    for (int j = 0; j < 16; ++j) {
        int l = wave * 16 + j;
        tl[l * 68 + lane] = po0 * w1o[l] + po1 * w1o[64 + l] + po2 * w1o[128 + l];
    }
    // ---- u-tile [lb][q] float4: wave w computes lb in [4w,4w+4) ----
#pragma unroll
    for (int k = 0; k < 4; ++k) {
        int lb = wave * 4 + k;
        float4 uv;
        {
            int l = lb * 4;
            uv.x = b1l[l+0] + pq0 * w1q[l+0] + pq1 * w1q[64 + l+0] + pq2 * w1q[128 + l+0];
            uv.y = b1l[l+1] + pq0 * w1q[l+1] + pq1 * w1q[64 + l+1] + pq2 * w1q[128 + l+1];
            uv.z = b1l[l+2] + pq0 * w1q[l+2] + pq1 * w1q[64 + l+2] + pq2 * w1q[128 + l+2];
            uv.w = b1l[l+3] + pq0 * w1q[l+3] + pq1 * w1q[64 + l+3] + pq2 * w1q[128 + l+3];
        }
        *(float4*)(ue + (size_t)(lb * 64 + lane) * 4) = uv;
    }
    __syncthreads();   // sync1: tiles ready

    // ---- Phase A: wave w -> o-slice [16w,16w+16), lane = q ----
    float lg[16];
#pragma unroll
    for (int o = 0; o < 16; ++o) lg[o] = 0.f;
    const int ow = wave * 16;
#pragma unroll
    for (int lb = 0; lb < 16; ++lb) {
        float4 u4 = *(const float4*)(ue + (size_t)(lb * 64 + lane) * 4);  // conflict-free b128
        float4 w4 = *(const float4*)(w2l + lb * 4);                        // broadcast
#pragma unroll
        for (int dl = 0; dl < 4; ++dl) {
            const int l = lb * 4 + dl;
            const float4* tr = (const float4*)(tl + l * 68 + ow);          // broadcast
            float ul = (dl == 0) ? u4.x : (dl == 1) ? u4.y : (dl == 2) ? u4.z : u4.w;
            float wl = (dl == 0) ? w4.x : (dl == 1) ? w4.y : (dl == 2) ? w4.z : w4.w;
#pragma unroll
            for (int j = 0; j < 4; ++j) {
                float4 t4 = tr[j];
                lg[4 * j + 0] += wl * fmaxf(ul + t4.x, 0.f);
                lg[4 * j + 1] += wl * fmaxf(ul + t4.y, 0.f);
                lg[4 * j + 2] += wl * fmaxf(ul + t4.z, 0.f);
                lg[4 * j + 3] += wl * fmaxf(ul + t4.w, 0.f);
            }
        }
    }
    // ---- mask + exp (logits O(1): raw exp safe) ----
    float e[16], spart = 0.f;
#pragma unroll
    for (int o = 0; o < 16; ++o) {
        float d0 = pq0 - po[ow + o];
        float d1 = pq1 - po[64 + ow + o];
        float d2 = pq2 - po[128 + ow + o];
        float dd = d0 * d0 + d1 * d1 + d2 * d2;
        float ev = (dd > 0.25f) ? 0.f : __expf(lg[o]);
        e[o] = ev; spart += ev;
    }
    __syncthreads();   // sync2: phase A done reading ue -> reuse as e-buf
#pragma unroll
    for (int o = 0; o < 16; ++o) ue[(size_t)(ow + o) * 64 + lane] = e[o];  // conflict-free
    sbuf[wave * 64 + lane] = spart;
    __syncthreads();   // sync3: e-buf ready

    // ---- Phase B: wave w -> l-slice [16w,16w+16), full 64 o's, raw h_obs ----
    float h0 = 0.f, h1 = 0.f, h2 = 0.f, h3 = 0.f, h4 = 0.f, h5 = 0.f, h6 = 0.f, h7 = 0.f;
    float h8 = 0.f, h9 = 0.f, hA = 0.f, hB = 0.f, hC = 0.f, hD = 0.f, hE = 0.f, hF = 0.f;
    const float* vb = h_obs + (size_t)obase * 64 + ow;   // ow doubles as l-offset
#pragma unroll 4
    for (int o = 0; o < 64; ++o) {
        float eo = ue[(size_t)o * 64 + lane];        // b32, lane-consecutive
        const float4* vr = (const float4*)(vb + (size_t)o * 64);  // wave-uniform, L2-hot
        float4 v0 = vr[0], v1 = vr[1], v2 = vr[2], v3 = vr[3];
        h0 += eo * v0.x; h1 += eo * v0.y; h2 += eo * v0.z; h3 += eo * v0.w;
        h4 += eo * v1.x; h5 += eo * v1.y; h6 += eo * v1.z; h7 += eo * v1.w;
        h8 += eo * v2.x; h9 += eo * v2.y; hA += eo * v2.z; hB += eo * v2.w;
        hC += eo * v3.x; hD += eo * v3.y; hE += eo * v3.z; hF += eo * v3.w;
    }

    // ---- store partials (disjoint per wave, no combine) ----
    float* hp = Ph + ((size_t)oc * NQ + (size_t)qg * 64 + lane) * 64 + ow;
    ((float4*)hp)[0] = make_float4(h0, h1, h2, h3);
    ((float4*)hp)[1] = make_float4(h4, h5, h6, h7);
    ((float4*)hp)[2] = make_float4(h8, h9, hA, hB);
    ((float4*)hp)[3] = make_float4(hC, hD, hE, hF);
    if (wave == 0) {
        float s = sbuf[lane] + sbuf[64 + lane] + sbuf[128 + lane] + sbuf[192 + lane];
        Ps[(size_t)oc * NQ + (size_t)qg * 64 + lane] = s;
    }
}

// ---------------------------------------------------------------------------
// Combine + Wv projection: g[q][k] = sum_c Ph[c][q][k]; s = sum_c Ps[c][q];
// out[q][l] = (g[q][:]/s) @ Wv + bv.  512 blocks; block = 4 q; wave w owns
// query w; Wv staged in LDS (lane-consecutive b32 reads, conflict-free).
// ---------------------------------------------------------------------------
__global__ __launch_bounds__(256, 2) void gano_comb(
    const float* __restrict__ Ph,
    const float* __restrict__ Ps,
    const float* __restrict__ Wv,
    const float* __restrict__ bv,
    float* __restrict__ out)
{
    __shared__ __align__(16) float wv[64 * 64];
    __shared__ __align__(16) float g[4 * 68];   // [qi][k], k=64 holds s; stride 68 (272B, 16B-aligned)
    const int tid  = threadIdx.x;
    const int lane = tid & 63;
    const int wave = tid >> 6;
    const int q0 = blockIdx.x * 4;
    {
        const float4* src = (const float4*)Wv;
        float4* dst = (float4*)wv;
#pragma unroll
        for (int k = 0; k < 4; ++k) dst[tid + k * 256] = src[tid + k * 256];
    }
    // chunk-sum: thread (qi=wave, k=lane): coalesced across lanes
    {
        const int qi = wave, k = lane;
        float acc = 0.f;
#pragma unroll
        for (int c = 0; c < NOC; ++c)
            acc += Ph[((size_t)c * NQ + q0 + qi) * 64 + k];
        g[qi * 68 + k] = acc;
        if (k == 0) {
            float ss = 0.f;
#pragma unroll
            for (int c = 0; c < NOC; ++c) ss += Ps[(size_t)c * NQ + q0 + qi];
            g[qi * 68 + 64] = ss;
        }
    }
    __syncthreads();
    // matvec: wave w -> query q0+w; lane = output latent l
    const float* gq = g + wave * 68;            // wave-uniform broadcast
    float inv = 1.0f / gq[64];
    float a0 = 0.f, a1 = 0.f, a2 = 0.f, a3 = 0.f;
#pragma unroll
    for (int kb = 0; kb < 16; ++kb) {
        float4 g4 = *(const float4*)(gq + kb * 4);
        a0 += g4.x * wv[(kb * 4 + 0) * 64 + lane];
        a1 += g4.y * wv[(kb * 4 + 1) * 64 + lane];
        a2 += g4.z * wv[(kb * 4 + 2) * 64 + lane];
        a3 += g4.w * wv[(kb * 4 + 3) * 64 + lane];
    }
    out[(size_t)(q0 + wave) * 64 + lane] = ((a0 + a1) + (a2 + a3)) * inv + bv[lane];
}

// ---------------------------------------------------------------------------
extern "C" void kernel_launch(void* const* d_in, const int* in_sizes, int n_in,
                              void* d_out, int out_size, void* d_ws, size_t ws_size,
                              hipStream_t stream) {
    const float* h_obs     = (const float*)d_in[0];
    // d_in[1] = x_obs (unused by reference)
    const float* pos_obs   = (const float*)d_in[2];
    const float* pos_query = (const float*)d_in[3];
    const float* W1        = (const float*)d_in[4];
    const float* b1        = (const float*)d_in[5];
    const float* W2        = (const float*)d_in[6];
    // d_in[7] = b2: constant shift, cancels in softmax
    const float* Wv        = (const float*)d_in[8];
    const float* bv        = (const float*)d_in[9];
    float* ws  = (float*)d_ws;
    float* out = (float*)d_out;

    gano_main<<<dim3(1024), dim3(256), 0, stream>>>(h_obs, pos_obs, pos_query, W1, b1, W2,
                                                    ws + OFF_PH, ws + OFF_PS);
    gano_comb<<<dim3(NQ / 4), dim3(256), 0, stream>>>(ws + OFF_PH, ws + OFF_PS, Wv, bv, out);
}